// Round 7
// baseline (1015.470 us; speedup 1.0000x reference)
//
#include <hip/hip_runtime.h>
#include <math.h>

// Dtype map (pinned by R0-R6 — the theory explaining all 7 results w/o flakes):
//   ALL INPUTS = float32 (bf16 misreads of fp32 data injected NaN in R2/R3/R5)
//   OUTPUT     = float32 (the reference's dtype; R4/R6 computed correctly but
//                serialized bf16 into the fp32 buffer — wrong positions + zero
//                tail reproduced the exact 5.1875 stub signature)
// The traceback's bf16 read path was source CONTEXT, not the executed branch.
// Internal compute fp32. Scratch in module __device__ globals, fully
// rewritten every call (d_ws untouched).

#define MAXS 2048

__device__ __align__(16) float g_pre[MAXS * 16];  // per-step gate pre-activations
__device__ __align__(16) float g_hs [MAXS * 4];   // per-step hidden state

// ---------------------------------------------------------------------------
// Phase 1: QCNN statevector sim. One 256-thread block per sequence element.
// 8-qubit state = 256 complex amps in LDS; thread i owns amplitude i
// (little-endian: qubit q = bit q of i, matching apply_1q's reshape).
// Feature map H+P(2x_q) is a product state -> direct init.
// Output: g_pre[s][l] = Ws[g][w][0]*<Z7> + b[g][w] + th[g][w], l = 4g+w.
// ---------------------------------------------------------------------------
__global__ __launch_bounds__(256) void qcnn_kernel(
    const float* __restrict__ sent, const float* __restrict__ wpar,
    const float* __restrict__ Wf, const float* __restrict__ bfv,
    const float* __restrict__ Wi, const float* __restrict__ bi,
    const float* __restrict__ Wu, const float* __restrict__ bu,
    const float* __restrict__ Wo, const float* __restrict__ bo,
    const float* __restrict__ thf, const float* __restrict__ thi,
    const float* __restrict__ thu, const float* __restrict__ tho)
{
    __shared__ float2 sv[256];
    __shared__ float  red[256];
    __shared__ float  sx[8];
    __shared__ float  sw[63];
    const int i = threadIdx.x;
    const int s = blockIdx.x;

    if (i < 8)                sx[i]      = sent[s * 8 + i];
    if (i >= 64 && i < 127)   sw[i - 64] = wpar[i - 64];
    __syncthreads();

    // init: amp[i] = (1/16) * exp(j * 2 * sum_{q: bit q of i set} x_q)
    float phi = 0.f;
    #pragma unroll
    for (int q = 0; q < 8; ++q)
        if ((i >> q) & 1) phi += sx[q];
    phi *= 2.f;
    float sp, cp;
    sincosf(phi, &sp, &cp);          // accurate: |phi| can reach ~50
    sv[i] = make_float2(cp * 0.0625f, sp * 0.0625f);

    // RZ(t) = diag(e^{-it/2}, e^{it/2}): thread-local (diagonal), no sync
    auto rz = [&](int q, float t) {
        float c = __cosf(0.5f * t), sn = __sinf(0.5f * t);
        float sgn = ((i >> q) & 1) ? -1.f : 1.f;
        float2 v = sv[i];
        sv[i] = make_float2(v.x * c + sgn * v.y * sn,
                            v.y * c - sgn * v.x * sn);
    };
    // RY(t) = [[c,-s],[s,c]] (real): partner pair through LDS
    auto ry = [&](int q, float t) {
        float c = __cosf(0.5f * t), sn = __sinf(0.5f * t);
        int m = 1 << q;
        __syncthreads();                 // prior writes visible
        float2 a0 = sv[i & ~m];
        float2 a1 = sv[i |  m];
        __syncthreads();                 // all reads done before overwrite
        float2 r;
        if ((i >> q) & 1) r = make_float2(sn * a0.x + c * a1.x, sn * a0.y + c * a1.y);
        else              r = make_float2(c * a0.x - sn * a1.x, c * a0.y - sn * a1.y);
        sv[i] = r;
    };
    // CNOT(c,t): permutation — if control bit set, read from target-flipped idx
    auto cnot = [&](int cq, int tq) {
        int src = ((i >> cq) & 1) ? (i ^ (1 << tq)) : i;
        __syncthreads();
        float2 v = sv[src];
        __syncthreads();
        sv[i] = v;
    };

    // Block wiring (CONV1, POOL1, CONV2, POOL2, CONV3, POOL3), k = 3*blk.
    // pool block == first 6 gates of conv block.
    constexpr int  AQ[21] = {0,2,4,6,1,3,5,7, 0,1,2,3, 0,2,1,3, 0,1, 0,1, 0};
    constexpr int  BQ[21] = {1,3,5,7,2,4,6,0, 4,5,6,7, 1,3,2,0, 2,3, 1,0, 1};
    constexpr bool CV[21] = {1,1,1,1,1,1,1,1, 0,0,0,0, 1,1,1,1, 0,0, 1,1, 0};
    const float PIH = 1.57079632679489662f;

    for (int blk = 0; blk < 21; ++blk) {
        const int a = AQ[blk], b = BQ[blk];
        const float p0 = sw[3*blk], p1 = sw[3*blk+1], p2 = sw[3*blk+2];
        rz(b, -PIH);
        cnot(b, a);
        rz(a, p0);
        ry(b, p1);
        cnot(a, b);
        ry(b, p2);
        if (CV[blk]) { cnot(b, a); rz(a, PIH); }   // uniform branch: barrier OK
    }

    // <Z_7> = sum_i |amp_i|^2 * (1 - 2*bit7(i))
    float2 v = sv[i];
    float p = (v.x * v.x + v.y * v.y) * (((i >> 7) & 1) ? -1.f : 1.f);
    red[i] = p;
    __syncthreads();
    #pragma unroll
    for (int off = 128; off > 0; off >>= 1) {
        if (i < off) red[i] += red[i + off];
        __syncthreads();
    }
    if (i < 16) {
        float e = red[0];
        int g = i >> 2, w = i & 3;
        const float* Wg  = (g == 0) ? Wf  : (g == 1) ? Wi  : (g == 2) ? Wu  : Wo;
        const float* bg  = (g == 0) ? bfv : (g == 1) ? bi  : (g == 2) ? bu  : bo;
        const float* thg = (g == 0) ? thf : (g == 1) ? thi : (g == 2) ? thu : tho;
        g_pre[s * 16 + i] = Wg[w * 5] * e + bg[w] + thg[w];
    }
}

// ---------------------------------------------------------------------------
// Phase 2: sequential QLSTM scan, single wave64.
// qlayer closed form (RX per wire + CNOT(0,1)(1,2)(2,3)(3,0) + <Z_w>),
// c_w = cos(theta_w):
//   z0 = c1*c2*c3 ; z1 = c0*c1 ; z2 = c0*c1*c2 ; z3 = c0*c1*c2*c3
// (Heisenberg conjugation of Z_w through the CNOT ring, re-verified.)
// Lane l = 4g+w owns theta[g][w]; lanes >=16 mirror l&15 (harmless).
// ---------------------------------------------------------------------------
__global__ __launch_bounds__(64) void lstm_kernel(
    const float* __restrict__ Wf, const float* __restrict__ Wi,
    const float* __restrict__ Wu, const float* __restrict__ Wo, int S)
{
    const int l   = threadIdx.x;
    const int lid = l & 15;
    const int g   = lid >> 2;
    const int w   = lid & 3;
    const float* Wg = (g == 0) ? Wf : (g == 1) ? Wi : (g == 2) ? Wu : Wo;
    const float Wh0 = Wg[w * 5 + 1], Wh1 = Wg[w * 5 + 2];
    const float Wh2 = Wg[w * 5 + 3], Wh3 = Wg[w * 5 + 4];
    const bool  tg  = (g == 2);          // u-gate uses tanh
    const int   base = lid & 12;

    float h0 = 0.f, h1 = 0.f, h2 = 0.f, h3 = 0.f;
    float cst = 0.f;                     // cell state for hidden unit w = l&3
    float cur = g_pre[lid];              // t = 0 (prefetched)

    for (int t = 0; t < S; ++t) {
        float nxt = (t + 1 < S) ? g_pre[(t + 1) * 16 + lid] : 0.f;  // prefetch
        float th = cur + Wh0 * h0 + Wh1 * h1 + Wh2 * h2 + Wh3 * h3;
        float d  = __cosf(th);
        // gather this gate's 4 cosines
        float d0 = __shfl(d, base + 0, 64);
        float d1 = __shfl(d, base + 1, 64);
        float d2 = __shfl(d, base + 2, 64);
        float d3 = __shfl(d, base + 3, 64);
        float p01 = d0 * d1, p012 = p01 * d2;
        float z = (w == 0) ? d1 * d2 * d3
                : (w == 1) ? p01
                : (w == 2) ? p012
                           : p012 * d3;
        // sigmoid for f/i/o, tanh(z) = 2*sigmoid(2z)-1 for u — branch-free
        float zz = tg ? z + z : z;
        float sg = 1.f / (1.f + __expf(-zz));
        float a  = tg ? sg + sg - 1.f : sg;
        // cross-gate gather for hidden unit w = l&3
        float af = __shfl(a, 0  + w, 64);
        float ai = __shfl(a, 4  + w, 64);
        float au = __shfl(a, 8  + w, 64);
        float ao = __shfl(a, 12 + w, 64);
        cst = af * cst + ai * au;
        float e2 = __expf(-2.f * cst);
        float hq = ao * (2.f / (1.f + e2) - 1.f);   // o * tanh(c)
        // broadcast new h (lanes 0..3 hold w = 0..3)
        h0 = __shfl(hq, 0, 64);
        h1 = __shfl(hq, 1, 64);
        h2 = __shfl(hq, 2, 64);
        h3 = __shfl(hq, 3, 64);
        if (l == 0)
            *(float4*)(g_hs + 4 * t) = make_float4(h0, h1, h2, h3);
        cur = nxt;
    }
}

// ---------------------------------------------------------------------------
// Phase 3: logits = hs @ Wt^T + bt over 32 tags; log_softmax over 32.
// One thread per timestep; Wt (32,4) / bt (32) staged in LDS; FP32 output.
// ---------------------------------------------------------------------------
__global__ __launch_bounds__(256) void head_kernel(
    const float* __restrict__ Wt, const float* __restrict__ bt,
    float* __restrict__ out, int S)
{
    __shared__ float sW[128];   // (32 tags, 4 hid) row-major
    __shared__ float sb[32];
    const int tid = threadIdx.x;
    if (tid < 128) sW[tid] = Wt[tid];
    if (tid < 32)  sb[tid] = bt[tid];
    __syncthreads();

    const int t = blockIdx.x * blockDim.x + tid;
    if (t >= S) return;
    const float h0 = g_hs[4*t+0], h1 = g_hs[4*t+1];
    const float h2 = g_hs[4*t+2], h3 = g_hs[4*t+3];
    float lg[32];
    float m = -1e30f;
    #pragma unroll
    for (int j = 0; j < 32; ++j) {
        lg[j] = sW[4*j+0]*h0 + sW[4*j+1]*h1 + sW[4*j+2]*h2 + sW[4*j+3]*h3 + sb[j];
        m = fmaxf(m, lg[j]);
    }
    float se = 0.f;
    #pragma unroll
    for (int j = 0; j < 32; ++j) se += __expf(lg[j] - m);
    float lse = m + __logf(se);
    #pragma unroll
    for (int j = 0; j < 32; ++j) out[32*t+j] = lg[j] - lse;
}

extern "C" void kernel_launch(void* const* d_in, const int* in_sizes, int n_in,
                              void* d_out, int out_size, void* d_ws, size_t ws_size,
                              hipStream_t stream)
{
    const float* sent = (const float*)d_in[0];
    const float* wq   = (const float*)d_in[1];
    const float* Wf   = (const float*)d_in[2];  const float* bfv = (const float*)d_in[3];
    const float* Wi   = (const float*)d_in[4];  const float* bi  = (const float*)d_in[5];
    const float* Wu   = (const float*)d_in[6];  const float* bu  = (const float*)d_in[7];
    const float* Wo   = (const float*)d_in[8];  const float* bo  = (const float*)d_in[9];
    const float* thf  = (const float*)d_in[10]; const float* thi = (const float*)d_in[11];
    const float* thu  = (const float*)d_in[12]; const float* tho = (const float*)d_in[13];
    const float* Wt   = (const float*)d_in[14]; const float* bt  = (const float*)d_in[15];

    int S = in_sizes[0] / 8;                // 2048 (B = 1)
    if (S > MAXS) S = MAXS;
    float* outp = (float*)d_out;            // fp32 output, 2048*32 elements

    qcnn_kernel<<<S, 256, 0, stream>>>(sent, wq, Wf, bfv, Wi, bi, Wu, bu, Wo, bo,
                                       thf, thi, thu, tho);
    lstm_kernel<<<1, 64, 0, stream>>>(Wf, Wi, Wu, Wo, S);
    head_kernel<<<(S + 255) / 256, 256, 0, stream>>>(Wt, bt, outp, S);
}

// Round 8
// 935.168 us; speedup vs baseline: 1.0859x; 1.0859x over previous
//
#include <hip/hip_runtime.h>
#include <math.h>

// Dtype map (pinned R0-R7): all inputs fp32, output fp32. Internal fp32.
// R7 passed at 1015 us with lstm_kernel = 896 us (88%): 1050 cyc/step, of
// which ~700 is 12 serialized ds_bpermute (__shfl) at LDS latency. R8
// replaces all cross-lane traffic with DPP (VALU-pipe, ~2-4 cyc):
//   - quad butterflies (quad_perm) for gate products + h broadcast
//   - row_ror:4/8/12 for the stride-4 cross-gate gather
// and collapses each QCNN conv/pool block into one precomputed 4x4 unitary
// (input-independent!), cutting qcnn barriers 196 -> ~43.

#define MAXS 2048

__device__ __align__(16) float g_pre[MAXS * 16];  // per-step gate pre-activations
__device__ __align__(16) float g_hs [MAXS * 4];   // per-step hidden state
__device__ float2 g_U[21 * 16];                   // 21 blocks x 4x4 complex

// DPP helper: ctrl must be a compile-time constant.
template <int CTRL>
__device__ __forceinline__ float dppf(float x) {
    return __int_as_float(__builtin_amdgcn_update_dpp(
        0, __float_as_int(x), CTRL, 0xF, 0xF, true));
}
// quad_perm encodings                 // out quad-lane k = in lane p[k]
#define QP_1032 0xB1                   // [1,0,3,2]  (swap pairs)
#define QP_2301 0x4E                   // [2,3,0,1]  (swap pair-groups)
#define QP_3210 0x1B                   // [3,2,1,0]  (reverse)
#define ROR4  0x124                    // out[l] = in[(l-4)&15]
#define ROR8  0x128
#define ROR12 0x12C

// Shared wiring tables
__constant__ int  cAQ[21] = {0,2,4,6,1,3,5,7, 0,1,2,3, 0,2,1,3, 0,1, 0,1, 0};
__constant__ int  cBQ[21] = {1,3,5,7,2,4,6,0, 4,5,6,7, 1,3,2,0, 2,3, 1,0, 1};
__constant__ int  cCV[21] = {1,1,1,1,1,1,1,1, 0,0,0,0, 1,1,1,1, 0,0, 1,1, 0};

// ---------------------------------------------------------------------------
// Phase 0: compose each conv/pool block's 4x4 complex unitary ONCE.
// Local basis m = bit_b*2 + bit_a. U <- G*U row ops per gate.
// conv: RZ_b(-pi/2) CN(b,a) RZ_a(p0) RY_b(p1) CN(a,b) RY_b(p2) CN(b,a) RZ_a(pi/2)
// pool: first 6 gates only.
// ---------------------------------------------------------------------------
__global__ void prep_kernel(const float* __restrict__ wpar) {
    const int b = threadIdx.x;
    if (b >= 21) return;
    const float p0 = wpar[3*b], p1 = wpar[3*b+1], p2 = wpar[3*b+2];
    float ur[4][4] = {}, ui[4][4] = {};
    #pragma unroll
    for (int m = 0; m < 4; ++m) ur[m][m] = 1.f;

    auto rzrow = [&](int bm, float t) {      // row m *= e^{(+/-)i t/2}
        float ch = cosf(0.5f*t), sh = sinf(0.5f*t);
        for (int m = 0; m < 4; ++m) {
            float pi_ = (m & bm) ? sh : -sh;
            for (int j = 0; j < 4; ++j) {
                float r = ur[m][j]*ch - ui[m][j]*pi_;
                float im = ur[m][j]*pi_ + ui[m][j]*ch;
                ur[m][j] = r; ui[m][j] = im;
            }
        }
    };
    auto ryrow = [&](int bm, float t) {      // mix rows (m0, m0|bm)
        float c = cosf(0.5f*t), s = sinf(0.5f*t);
        for (int m0 = 0; m0 < 4; ++m0) {
            if (m0 & bm) continue;
            int m1 = m0 | bm;
            for (int j = 0; j < 4; ++j) {
                float r0 = ur[m0][j], i0 = ui[m0][j];
                float r1 = ur[m1][j], i1 = ui[m1][j];
                ur[m0][j] = c*r0 - s*r1; ui[m0][j] = c*i0 - s*i1;
                ur[m1][j] = s*r0 + c*r1; ui[m1][j] = s*i0 + c*i1;
            }
        }
    };
    auto swrows = [&](int x, int y) {
        for (int j = 0; j < 4; ++j) {
            float tr = ur[x][j]; ur[x][j] = ur[y][j]; ur[y][j] = tr;
            float ti = ui[x][j]; ui[x][j] = ui[y][j]; ui[y][j] = ti;
        }
    };

    const float PIH = 1.57079632679489662f;
    rzrow(2, -PIH);          // RZ on b
    swrows(2, 3);            // CNOT(b->a): flip a where b=1
    rzrow(1, p0);            // RZ on a
    ryrow(2, p1);            // RY on b
    swrows(1, 3);            // CNOT(a->b): flip b where a=1
    ryrow(2, p2);            // RY on b
    if (cCV[b]) { swrows(2, 3); rzrow(1, PIH); }

    for (int m = 0; m < 4; ++m)
        for (int j = 0; j < 4; ++j)
            g_U[(b*4 + m)*4 + j] = make_float2(ur[m][j], ui[m][j]);
}

// ---------------------------------------------------------------------------
// Phase 1: QCNN. One 256-thread block per sequence element; thread i owns
// amplitude i. Each of the 21 two-qubit blocks = one 4x4 complex matvec on
// the (bit_a, bit_b) subspace: 2 barriers per block instead of ~10.
// ---------------------------------------------------------------------------
__global__ __launch_bounds__(256) void qcnn_kernel(
    const float* __restrict__ sent,
    const float* __restrict__ Wf, const float* __restrict__ bfv,
    const float* __restrict__ Wi, const float* __restrict__ bi,
    const float* __restrict__ Wu, const float* __restrict__ bu,
    const float* __restrict__ Wo, const float* __restrict__ bo,
    const float* __restrict__ thf, const float* __restrict__ thi,
    const float* __restrict__ thu, const float* __restrict__ tho)
{
    __shared__ float2 sv[256];
    __shared__ float2 sU[336];
    __shared__ float  red[256];
    __shared__ float  sx[8];
    const int i = threadIdx.x;
    const int s = blockIdx.x;

    if (i < 8) sx[i] = sent[s * 8 + i];
    sU[i] = g_U[i];
    if (i < 80) sU[256 + i] = g_U[256 + i];
    __syncthreads();

    // init: amp[i] = (1/16) * exp(j * 2 * sum_{q: bit q of i set} x_q)
    float phi = 0.f;
    #pragma unroll
    for (int q = 0; q < 8; ++q)
        if ((i >> q) & 1) phi += sx[q];
    phi *= 2.f;
    float sp, cp;
    sincosf(phi, &sp, &cp);
    float2 my = make_float2(cp * 0.0625f, sp * 0.0625f);
    sv[i] = my;

    for (int blk = 0; blk < 21; ++blk) {
        const int a = cAQ[blk], bq = cBQ[blk];
        const int ma = 1 << a, mb = 1 << bq;
        const int m  = (((i >> bq) & 1) << 1) | ((i >> a) & 1);
        const int i0 = i & ~(ma | mb);
        __syncthreads();                       // prior writes visible
        float2 a0 = sv[i0];
        float2 a1 = sv[i0 | ma];
        float2 a2 = sv[i0 | mb];
        float2 a3 = sv[i0 | ma | mb];
        const float2* Um = &sU[blk*16 + m*4];
        float2 U0 = Um[0], U1 = Um[1], U2 = Um[2], U3 = Um[3];
        float re = U0.x*a0.x - U0.y*a0.y + U1.x*a1.x - U1.y*a1.y
                 + U2.x*a2.x - U2.y*a2.y + U3.x*a3.x - U3.y*a3.y;
        float im = U0.x*a0.y + U0.y*a0.x + U1.x*a1.y + U1.y*a1.x
                 + U2.x*a2.y + U2.y*a2.x + U3.x*a3.y + U3.y*a3.x;
        __syncthreads();                       // all reads done
        sv[i] = make_float2(re, im);
    }
    __syncthreads();

    // <Z_7> = sum_i |amp_i|^2 * (1 - 2*bit7(i))
    float2 v = sv[i];
    red[i] = (v.x*v.x + v.y*v.y) * (((i >> 7) & 1) ? -1.f : 1.f);
    __syncthreads();
    #pragma unroll
    for (int off = 128; off > 0; off >>= 1) {
        if (i < off) red[i] += red[i + off];
        __syncthreads();
    }
    if (i < 16) {
        float e = red[0];
        int g = i >> 2, w = i & 3;
        const float* Wg  = (g == 0) ? Wf  : (g == 1) ? Wi  : (g == 2) ? Wu  : Wo;
        const float* bg  = (g == 0) ? bfv : (g == 1) ? bi  : (g == 2) ? bu  : bo;
        const float* thg = (g == 0) ? thf : (g == 1) ? thi : (g == 2) ? thu : tho;
        g_pre[s * 16 + i] = Wg[w * 5] * e + bg[w] + thg[w];
    }
}

// ---------------------------------------------------------------------------
// Phase 2: sequential QLSTM scan, single wave64, ALL cross-lane via DPP.
// Lane l: lid=l&15, gate g=lid>>2, wire w=lid&3 (lanes 16-63 are replicas —
// quad_perm and row ops act within quads/rows of 16, so replicas stay
// coherent). qlayer closed form: z0=c1c2c3, z1=c0c1, z2=c0c1c2, z3=c0c1c2c3.
// ---------------------------------------------------------------------------
__global__ __launch_bounds__(64) void lstm_kernel(
    const float* __restrict__ Wf, const float* __restrict__ Wi,
    const float* __restrict__ Wu, const float* __restrict__ Wo, int S)
{
    const int l   = threadIdx.x;
    const int lid = l & 15;
    const int g   = lid >> 2;
    const int w   = lid & 3;
    const float* Wg = (g == 0) ? Wf : (g == 1) ? Wi : (g == 2) ? Wu : Wo;
    // weights permuted to match DPP broadcast registers: hb_k holds h_{w^k}
    const float Wp0 = Wg[w*5 + 1 + (w    )];
    const float Wp1 = Wg[w*5 + 1 + (w ^ 1)];
    const float Wp2 = Wg[w*5 + 1 + (w ^ 2)];
    const float Wp3 = Wg[w*5 + 1 + (w ^ 3)];
    const bool  tg  = (g == 2);          // u-gate uses tanh

    float hs = 0.f, hb1 = 0.f, hb2 = 0.f, hb3 = 0.f;  // h_w, h_{w^1}, h_{w^2}, h_{w^3}
    float cst = 0.f;                     // cell state for wire w
    float cur = g_pre[lid];              // t = 0 (prefetched)

    for (int t = 0; t < S; ++t) {
        float nxt = (t + 1 < S) ? g_pre[(t + 1) * 16 + lid] : 0.f;  // prefetch
        float th = fmaf(Wp0, hs, fmaf(Wp1, hb1, fmaf(Wp2, hb2, fmaf(Wp3, hb3, cur))));
        float d  = __cosf(th);
        // quad butterfly: z-product per (g,w)
        float v1 = dppf<QP_1032>(d);     // cos of wire w^1
        float pp = d * v1;               // pair product
        float v2 = dppf<QP_2301>(pp);    // other pair's product
        float z = (w == 0) ? v1 * v2
                : (w == 1) ? pp
                : (w == 2) ? v2 * d
                           : pp * v2;
        // activation: sigmoid for gates 0,1,3; tanh (=2*sig(2z)-1) for gate 2
        float zz = tg ? z + z : z;
        float sg = 1.f / (1.f + __expf(-zz));
        float a  = tg ? sg + sg - 1.f : sg;
        // cross-gate gather via row rotate: r4 = gate g-1, r8 = g-2, r12 = g-3
        float r4  = dppf<ROR4 >(a);
        float r8  = dppf<ROR8 >(a);
        float r12 = dppf<ROR12>(a);
        // label by target gate k: register index (g-k)&3 -> {a,r4,r8,r12}
        float af = (g == 0) ? a : (g == 1) ? r4 : (g == 2) ? r8 : r12;
        float ai = (g == 1) ? a : (g == 2) ? r4 : (g == 3) ? r8 : r12;
        float au = (g == 2) ? a : (g == 3) ? r4 : (g == 0) ? r8 : r12;
        float ao = (g == 3) ? a : (g == 0) ? r4 : (g == 1) ? r8 : r12;
        cst = fmaf(af, cst, ai * au);
        float e2 = __expf(-2.f * cst);
        float hq = ao * (2.f / (1.f + e2) - 1.f);   // o * tanh(c)
        // broadcast within quad: every lane gets all four wires' h
        hs  = hq;
        hb1 = dppf<QP_1032>(hq);
        hb2 = dppf<QP_2301>(hq);
        hb3 = dppf<QP_3210>(hq);
        if (l == 0)   // lane 0: w=0 -> (hs,hb1,hb2,hb3) = (h0,h1,h2,h3)
            *(float4*)(g_hs + 4 * t) = make_float4(hs, hb1, hb2, hb3);
        cur = nxt;
    }
}

// ---------------------------------------------------------------------------
// Phase 3: logits = hs @ Wt^T + bt over 32 tags; log_softmax over 32. fp32 out.
// ---------------------------------------------------------------------------
__global__ __launch_bounds__(256) void head_kernel(
    const float* __restrict__ Wt, const float* __restrict__ bt,
    float* __restrict__ out, int S)
{
    __shared__ float sW[128];   // (32 tags, 4 hid) row-major
    __shared__ float sb[32];
    const int tid = threadIdx.x;
    if (tid < 128) sW[tid] = Wt[tid];
    if (tid < 32)  sb[tid] = bt[tid];
    __syncthreads();

    const int t = blockIdx.x * blockDim.x + tid;
    if (t >= S) return;
    const float h0 = g_hs[4*t+0], h1 = g_hs[4*t+1];
    const float h2 = g_hs[4*t+2], h3 = g_hs[4*t+3];
    float lg[32];
    float m = -1e30f;
    #pragma unroll
    for (int j = 0; j < 32; ++j) {
        lg[j] = sW[4*j+0]*h0 + sW[4*j+1]*h1 + sW[4*j+2]*h2 + sW[4*j+3]*h3 + sb[j];
        m = fmaxf(m, lg[j]);
    }
    float se = 0.f;
    #pragma unroll
    for (int j = 0; j < 32; ++j) se += __expf(lg[j] - m);
    float lse = m + __logf(se);
    #pragma unroll
    for (int j = 0; j < 32; ++j) out[32*t+j] = lg[j] - lse;
}

extern "C" void kernel_launch(void* const* d_in, const int* in_sizes, int n_in,
                              void* d_out, int out_size, void* d_ws, size_t ws_size,
                              hipStream_t stream)
{
    const float* sent = (const float*)d_in[0];
    const float* wq   = (const float*)d_in[1];
    const float* Wf   = (const float*)d_in[2];  const float* bfv = (const float*)d_in[3];
    const float* Wi   = (const float*)d_in[4];  const float* bi  = (const float*)d_in[5];
    const float* Wu   = (const float*)d_in[6];  const float* bu  = (const float*)d_in[7];
    const float* Wo   = (const float*)d_in[8];  const float* bo  = (const float*)d_in[9];
    const float* thf  = (const float*)d_in[10]; const float* thi = (const float*)d_in[11];
    const float* thu  = (const float*)d_in[12]; const float* tho = (const float*)d_in[13];
    const float* Wt   = (const float*)d_in[14]; const float* bt  = (const float*)d_in[15];

    int S = in_sizes[0] / 8;                // 2048 (B = 1)
    if (S > MAXS) S = MAXS;
    float* outp = (float*)d_out;

    prep_kernel<<<1, 32, 0, stream>>>(wq);
    qcnn_kernel<<<S, 256, 0, stream>>>(sent, Wf, bfv, Wi, bi, Wu, bu, Wo, bo,
                                       thf, thi, thu, tho);
    lstm_kernel<<<1, 64, 0, stream>>>(Wf, Wi, Wu, Wo, S);
    head_kernel<<<(S + 255) / 256, 256, 0, stream>>>(Wt, bt, outp, S);
}

// Round 9
// 598.547 us; speedup vs baseline: 1.6966x; 1.5624x over previous
//
#include <hip/hip_runtime.h>
#include <math.h>

// Dtype map (pinned R0-R7): all inputs fp32, output fp32. Internal fp32.
// R8 post-mortem: lstm is LOAD-LATENCY-bound, not shuffle-bound — one
// ~900-cyc HBM/remote-L2 fetch per step, exposed (1-iteration prefetch
// slack, zero MLP on a single wave). R9: transpose staging to
// g_preT[lid][t] and prefetch float4 chunks 3 deep (12 iterations of
// slack, 3 loads in flight) so the scan runs at its VALU dependency-chain
// rate. Cross-lane stays all-DPP (bit-exact verified in R8, absmax 0.0).

#define MAXS 2048

__device__ __align__(16) float g_preT[16 * MAXS]; // [lid][t] gate pre-activations
__device__ __align__(16) float g_hs [MAXS * 4];   // per-step hidden state
__device__ float2 g_U[21 * 16];                   // 21 blocks x 4x4 complex

// DPP helper: ctrl must be a compile-time constant.
template <int CTRL>
__device__ __forceinline__ float dppf(float x) {
    return __int_as_float(__builtin_amdgcn_update_dpp(
        0, __float_as_int(x), CTRL, 0xF, 0xF, true));
}
// quad_perm encodings                 // out quad-lane k = in lane p[k]
#define QP_1032 0xB1                   // [1,0,3,2]  (swap pairs)
#define QP_2301 0x4E                   // [2,3,0,1]  (swap pair-groups)
#define QP_3210 0x1B                   // [3,2,1,0]  (reverse)
#define ROR4  0x124                    // out[l] = in[(l-4)&15]
#define ROR8  0x128
#define ROR12 0x12C

// Shared wiring tables
__constant__ int  cAQ[21] = {0,2,4,6,1,3,5,7, 0,1,2,3, 0,2,1,3, 0,1, 0,1, 0};
__constant__ int  cBQ[21] = {1,3,5,7,2,4,6,0, 4,5,6,7, 1,3,2,0, 2,3, 1,0, 1};
__constant__ int  cCV[21] = {1,1,1,1,1,1,1,1, 0,0,0,0, 1,1,1,1, 0,0, 1,1, 0};

// ---------------------------------------------------------------------------
// Phase 0: compose each conv/pool block's 4x4 complex unitary ONCE.
// Local basis m = bit_b*2 + bit_a. U <- G*U row ops per gate.
// ---------------------------------------------------------------------------
__global__ void prep_kernel(const float* __restrict__ wpar) {
    const int b = threadIdx.x;
    if (b >= 21) return;
    const float p0 = wpar[3*b], p1 = wpar[3*b+1], p2 = wpar[3*b+2];
    float ur[4][4] = {}, ui[4][4] = {};
    #pragma unroll
    for (int m = 0; m < 4; ++m) ur[m][m] = 1.f;

    auto rzrow = [&](int bm, float t) {      // row m *= e^{(+/-)i t/2}
        float ch = cosf(0.5f*t), sh = sinf(0.5f*t);
        for (int m = 0; m < 4; ++m) {
            float pi_ = (m & bm) ? sh : -sh;
            for (int j = 0; j < 4; ++j) {
                float r = ur[m][j]*ch - ui[m][j]*pi_;
                float im = ur[m][j]*pi_ + ui[m][j]*ch;
                ur[m][j] = r; ui[m][j] = im;
            }
        }
    };
    auto ryrow = [&](int bm, float t) {      // mix rows (m0, m0|bm)
        float c = cosf(0.5f*t), s = sinf(0.5f*t);
        for (int m0 = 0; m0 < 4; ++m0) {
            if (m0 & bm) continue;
            int m1 = m0 | bm;
            for (int j = 0; j < 4; ++j) {
                float r0 = ur[m0][j], i0 = ui[m0][j];
                float r1 = ur[m1][j], i1 = ui[m1][j];
                ur[m0][j] = c*r0 - s*r1; ui[m0][j] = c*i0 - s*i1;
                ur[m1][j] = s*r0 + c*r1; ui[m1][j] = s*i0 + c*i1;
            }
        }
    };
    auto swrows = [&](int x, int y) {
        for (int j = 0; j < 4; ++j) {
            float tr = ur[x][j]; ur[x][j] = ur[y][j]; ur[y][j] = tr;
            float ti = ui[x][j]; ui[x][j] = ui[y][j]; ui[y][j] = ti;
        }
    };

    const float PIH = 1.57079632679489662f;
    rzrow(2, -PIH);          // RZ on b
    swrows(2, 3);            // CNOT(b->a): flip a where b=1
    rzrow(1, p0);            // RZ on a
    ryrow(2, p1);            // RY on b
    swrows(1, 3);            // CNOT(a->b): flip b where a=1
    ryrow(2, p2);            // RY on b
    if (cCV[b]) { swrows(2, 3); rzrow(1, PIH); }

    for (int m = 0; m < 4; ++m)
        for (int j = 0; j < 4; ++j)
            g_U[(b*4 + m)*4 + j] = make_float2(ur[m][j], ui[m][j]);
}

// ---------------------------------------------------------------------------
// Phase 1: QCNN. One 256-thread block per sequence element; thread i owns
// amplitude i. Each of the 21 two-qubit blocks = one 4x4 complex matvec on
// the (bit_a, bit_b) subspace. Output written TRANSPOSED: g_preT[l][s].
// ---------------------------------------------------------------------------
__global__ __launch_bounds__(256) void qcnn_kernel(
    const float* __restrict__ sent,
    const float* __restrict__ Wf, const float* __restrict__ bfv,
    const float* __restrict__ Wi, const float* __restrict__ bi,
    const float* __restrict__ Wu, const float* __restrict__ bu,
    const float* __restrict__ Wo, const float* __restrict__ bo,
    const float* __restrict__ thf, const float* __restrict__ thi,
    const float* __restrict__ thu, const float* __restrict__ tho)
{
    __shared__ float2 sv[256];
    __shared__ float2 sU[336];
    __shared__ float  red[256];
    __shared__ float  sx[8];
    const int i = threadIdx.x;
    const int s = blockIdx.x;

    if (i < 8) sx[i] = sent[s * 8 + i];
    sU[i] = g_U[i];
    if (i < 80) sU[256 + i] = g_U[256 + i];
    __syncthreads();

    // init: amp[i] = (1/16) * exp(j * 2 * sum_{q: bit q of i set} x_q)
    float phi = 0.f;
    #pragma unroll
    for (int q = 0; q < 8; ++q)
        if ((i >> q) & 1) phi += sx[q];
    phi *= 2.f;
    float sp, cp;
    sincosf(phi, &sp, &cp);
    sv[i] = make_float2(cp * 0.0625f, sp * 0.0625f);

    for (int blk = 0; blk < 21; ++blk) {
        const int a = cAQ[blk], bq = cBQ[blk];
        const int ma = 1 << a, mb = 1 << bq;
        const int m  = (((i >> bq) & 1) << 1) | ((i >> a) & 1);
        const int i0 = i & ~(ma | mb);
        __syncthreads();                       // prior writes visible
        float2 a0 = sv[i0];
        float2 a1 = sv[i0 | ma];
        float2 a2 = sv[i0 | mb];
        float2 a3 = sv[i0 | ma | mb];
        const float2* Um = &sU[blk*16 + m*4];
        float2 U0 = Um[0], U1 = Um[1], U2 = Um[2], U3 = Um[3];
        float re = U0.x*a0.x - U0.y*a0.y + U1.x*a1.x - U1.y*a1.y
                 + U2.x*a2.x - U2.y*a2.y + U3.x*a3.x - U3.y*a3.y;
        float im = U0.x*a0.y + U0.y*a0.x + U1.x*a1.y + U1.y*a1.x
                 + U2.x*a2.y + U2.y*a2.x + U3.x*a3.y + U3.y*a3.x;
        __syncthreads();                       // all reads done
        sv[i] = make_float2(re, im);
    }
    __syncthreads();

    // <Z_7> = sum_i |amp_i|^2 * (1 - 2*bit7(i))
    float2 v = sv[i];
    red[i] = (v.x*v.x + v.y*v.y) * (((i >> 7) & 1) ? -1.f : 1.f);
    __syncthreads();
    #pragma unroll
    for (int off = 128; off > 0; off >>= 1) {
        if (i < off) red[i] += red[i + off];
        __syncthreads();
    }
    if (i < 16) {
        float e = red[0];
        int g = i >> 2, w = i & 3;
        const float* Wg  = (g == 0) ? Wf  : (g == 1) ? Wi  : (g == 2) ? Wu  : Wo;
        const float* bg  = (g == 0) ? bfv : (g == 1) ? bi  : (g == 2) ? bu  : bo;
        const float* thg = (g == 0) ? thf : (g == 1) ? thi : (g == 2) ? thu : tho;
        g_preT[i * MAXS + s] = Wg[w * 5] * e + bg[w] + thg[w];   // transposed
    }
}

// ---------------------------------------------------------------------------
// Phase 2: sequential QLSTM scan, single wave64, all-DPP cross-lane.
// Input staged as g_preT[lid][t]: each lane loads float4 = 4 steps of its
// own pre-activation, pipelined 3 chunks (12 steps) deep -> ~900-cyc fetch
// latency fully hidden; loop runs at VALU-chain rate.
// qlayer closed form: z0=c1c2c3, z1=c0c1, z2=c0c1c2, z3=c0c1c2c3.
// ---------------------------------------------------------------------------
__global__ __launch_bounds__(64) void lstm_kernel(
    const float* __restrict__ Wf, const float* __restrict__ Wi,
    const float* __restrict__ Wu, const float* __restrict__ Wo, int S)
{
    const int l   = threadIdx.x;
    const int lid = l & 15;
    const int g   = lid >> 2;
    const int w   = lid & 3;
    const float* Wg = (g == 0) ? Wf : (g == 1) ? Wi : (g == 2) ? Wu : Wo;
    // weights permuted to match DPP broadcast registers: hb_k holds h_{w^k}
    const float Wp0 = Wg[w*5 + 1 + (w    )];
    const float Wp1 = Wg[w*5 + 1 + (w ^ 1)];
    const float Wp2 = Wg[w*5 + 1 + (w ^ 2)];
    const float Wp3 = Wg[w*5 + 1 + (w ^ 3)];
    const bool  tg  = (g == 2);          // u-gate uses tanh

    float hs = 0.f, hb1 = 0.f, hb2 = 0.f, hb3 = 0.f;
    float cst = 0.f;

    const float4* rowp = (const float4*)(g_preT + lid * MAXS);
    const int nch = S >> 2;              // S=2048 -> 512 chunks of 4 steps
    const float4 Z4 = make_float4(0.f, 0.f, 0.f, 0.f);
    float4 c0 = (0 < nch) ? rowp[0] : Z4;
    float4 c1 = (1 < nch) ? rowp[1] : Z4;
    float4 c2 = (2 < nch) ? rowp[2] : Z4;

    for (int ch = 0; ch < nch; ++ch) {
        float4 nx = (ch + 3 < nch) ? rowp[ch + 3] : Z4;   // 12-step prefetch
        float pres[4];
        *(float4*)pres = c0;
        #pragma unroll
        for (int j = 0; j < 4; ++j) {
            float th = fmaf(Wp0, hs, fmaf(Wp1, hb1,
                        fmaf(Wp2, hb2, fmaf(Wp3, hb3, pres[j]))));
            float d  = __cosf(th);
            // quad butterfly: z-product per (g,w)
            float v1 = dppf<QP_1032>(d);     // cos of wire w^1
            float pp = d * v1;               // pair product
            float v2 = dppf<QP_2301>(pp);    // other pair's product
            float z = (w == 0) ? v1 * v2
                    : (w == 1) ? pp
                    : (w == 2) ? v2 * d
                               : pp * v2;
            // sigmoid for gates f/i/o; tanh (=2*sig(2z)-1) for gate u
            float zz = tg ? z + z : z;
            float sg = 1.f / (1.f + __expf(-zz));
            float a  = tg ? sg + sg - 1.f : sg;
            // cross-gate gather: r4 = gate g-1, r8 = g-2, r12 = g-3
            float r4  = dppf<ROR4 >(a);
            float r8  = dppf<ROR8 >(a);
            float r12 = dppf<ROR12>(a);
            float af = (g == 0) ? a : (g == 1) ? r4 : (g == 2) ? r8 : r12;
            float ai = (g == 1) ? a : (g == 2) ? r4 : (g == 3) ? r8 : r12;
            float au = (g == 2) ? a : (g == 3) ? r4 : (g == 0) ? r8 : r12;
            float ao = (g == 3) ? a : (g == 0) ? r4 : (g == 1) ? r8 : r12;
            cst = fmaf(af, cst, ai * au);
            float e2 = __expf(-2.f * cst);
            float hq = ao * (2.f / (1.f + e2) - 1.f);   // o * tanh(c)
            // broadcast within quad
            hs  = hq;
            hb1 = dppf<QP_1032>(hq);
            hb2 = dppf<QP_2301>(hq);
            hb3 = dppf<QP_3210>(hq);
            if (l == 0)
                *(float4*)(g_hs + 4 * (ch * 4 + j)) = make_float4(hs, hb1, hb2, hb3);
        }
        c0 = c1; c1 = c2; c2 = nx;
    }
    // scalar tail for S not divisible by 4 (S=2048: no-op)
    for (int t = nch * 4; t < S; ++t) {
        float cur = g_preT[lid * MAXS + t];
        float th = fmaf(Wp0, hs, fmaf(Wp1, hb1, fmaf(Wp2, hb2, fmaf(Wp3, hb3, cur))));
        float d  = __cosf(th);
        float v1 = dppf<QP_1032>(d);
        float pp = d * v1;
        float v2 = dppf<QP_2301>(pp);
        float z = (w == 0) ? v1 * v2 : (w == 1) ? pp : (w == 2) ? v2 * d : pp * v2;
        float zz = tg ? z + z : z;
        float sg = 1.f / (1.f + __expf(-zz));
        float a  = tg ? sg + sg - 1.f : sg;
        float r4  = dppf<ROR4 >(a);
        float r8  = dppf<ROR8 >(a);
        float r12 = dppf<ROR12>(a);
        float af = (g == 0) ? a : (g == 1) ? r4 : (g == 2) ? r8 : r12;
        float ai = (g == 1) ? a : (g == 2) ? r4 : (g == 3) ? r8 : r12;
        float au = (g == 2) ? a : (g == 3) ? r4 : (g == 0) ? r8 : r12;
        float ao = (g == 3) ? a : (g == 0) ? r4 : (g == 1) ? r8 : r12;
        cst = fmaf(af, cst, ai * au);
        float e2 = __expf(-2.f * cst);
        float hq = ao * (2.f / (1.f + e2) - 1.f);
        hs  = hq;
        hb1 = dppf<QP_1032>(hq);
        hb2 = dppf<QP_2301>(hq);
        hb3 = dppf<QP_3210>(hq);
        if (l == 0)
            *(float4*)(g_hs + 4 * t) = make_float4(hs, hb1, hb2, hb3);
    }
}

// ---------------------------------------------------------------------------
// Phase 3: logits = hs @ Wt^T + bt over 32 tags; log_softmax over 32. fp32 out.
// ---------------------------------------------------------------------------
__global__ __launch_bounds__(256) void head_kernel(
    const float* __restrict__ Wt, const float* __restrict__ bt,
    float* __restrict__ out, int S)
{
    __shared__ float sW[128];   // (32 tags, 4 hid) row-major
    __shared__ float sb[32];
    const int tid = threadIdx.x;
    if (tid < 128) sW[tid] = Wt[tid];
    if (tid < 32)  sb[tid] = bt[tid];
    __syncthreads();

    const int t = blockIdx.x * blockDim.x + tid;
    if (t >= S) return;
    const float h0 = g_hs[4*t+0], h1 = g_hs[4*t+1];
    const float h2 = g_hs[4*t+2], h3 = g_hs[4*t+3];
    float lg[32];
    float m = -1e30f;
    #pragma unroll
    for (int j = 0; j < 32; ++j) {
        lg[j] = sW[4*j+0]*h0 + sW[4*j+1]*h1 + sW[4*j+2]*h2 + sW[4*j+3]*h3 + sb[j];
        m = fmaxf(m, lg[j]);
    }
    float se = 0.f;
    #pragma unroll
    for (int j = 0; j < 32; ++j) se += __expf(lg[j] - m);
    float lse = m + __logf(se);
    #pragma unroll
    for (int j = 0; j < 32; ++j) out[32*t+j] = lg[j] - lse;
}

extern "C" void kernel_launch(void* const* d_in, const int* in_sizes, int n_in,
                              void* d_out, int out_size, void* d_ws, size_t ws_size,
                              hipStream_t stream)
{
    const float* sent = (const float*)d_in[0];
    const float* wq   = (const float*)d_in[1];
    const float* Wf   = (const float*)d_in[2];  const float* bfv = (const float*)d_in[3];
    const float* Wi   = (const float*)d_in[4];  const float* bi  = (const float*)d_in[5];
    const float* Wu   = (const float*)d_in[6];  const float* bu  = (const float*)d_in[7];
    const float* Wo   = (const float*)d_in[8];  const float* bo  = (const float*)d_in[9];
    const float* thf  = (const float*)d_in[10]; const float* thi = (const float*)d_in[11];
    const float* thu  = (const float*)d_in[12]; const float* tho = (const float*)d_in[13];
    const float* Wt   = (const float*)d_in[14]; const float* bt  = (const float*)d_in[15];

    int S = in_sizes[0] / 8;                // 2048 (B = 1)
    if (S > MAXS) S = MAXS;
    float* outp = (float*)d_out;

    prep_kernel<<<1, 32, 0, stream>>>(wq);
    qcnn_kernel<<<S, 256, 0, stream>>>(sent, Wf, bfv, Wi, bi, Wu, bu, Wo, bo,
                                       thf, thi, thu, tho);
    lstm_kernel<<<1, 64, 0, stream>>>(Wf, Wi, Wu, Wo, S);
    head_kernel<<<(S + 255) / 256, 256, 0, stream>>>(Wt, bt, outp, S);
}

// Round 10
// 595.201 us; speedup vs baseline: 1.7061x; 1.0056x over previous
//
#include <hip/hip_runtime.h>
#include <math.h>

// Dtype map (pinned R0-R7): all inputs fp32, output fp32. Internal fp32.
// R9 post-mortem: 3-chunk rotating prefetch still exposed ~300 cyc/chunk
// (wait lands at end of the issuing chunk: 4-step slack < 900-cyc latency),
// VALUBusy 0.05% => active CU idle ~87%. R10: 16-step super-chunk register
// double-buffer (slack 16 steps >> latency, one vmcnt wait per 16 steps)
// + chain micro-surgery (tree dot product, fma-based activation selects).
// Cross-lane stays all-DPP (bit-exact, absmax 0.0 in R8/R9).

#define MAXS 2048

__device__ __align__(16) float g_preT[16 * MAXS]; // [lid][t] gate pre-activations
__device__ __align__(16) float g_hs [MAXS * 4];   // per-step hidden state
__device__ float2 g_U[21 * 16];                   // 21 blocks x 4x4 complex

// DPP helper: ctrl must be a compile-time constant.
template <int CTRL>
__device__ __forceinline__ float dppf(float x) {
    return __int_as_float(__builtin_amdgcn_update_dpp(
        0, __float_as_int(x), CTRL, 0xF, 0xF, true));
}
// quad_perm encodings                 // out quad-lane k = in lane p[k]
#define QP_1032 0xB1                   // [1,0,3,2]  (swap pairs)
#define QP_2301 0x4E                   // [2,3,0,1]  (swap pair-groups)
#define QP_3210 0x1B                   // [3,2,1,0]  (reverse)
#define ROR4  0x124                    // out[l] = in[(l-4)&15]
#define ROR8  0x128
#define ROR12 0x12C

// Shared wiring tables
__constant__ int  cAQ[21] = {0,2,4,6,1,3,5,7, 0,1,2,3, 0,2,1,3, 0,1, 0,1, 0};
__constant__ int  cBQ[21] = {1,3,5,7,2,4,6,0, 4,5,6,7, 1,3,2,0, 2,3, 1,0, 1};
__constant__ int  cCV[21] = {1,1,1,1,1,1,1,1, 0,0,0,0, 1,1,1,1, 0,0, 1,1, 0};

// ---------------------------------------------------------------------------
// Phase 0: compose each conv/pool block's 4x4 complex unitary ONCE.
// ---------------------------------------------------------------------------
__global__ void prep_kernel(const float* __restrict__ wpar) {
    const int b = threadIdx.x;
    if (b >= 21) return;
    const float p0 = wpar[3*b], p1 = wpar[3*b+1], p2 = wpar[3*b+2];
    float ur[4][4] = {}, ui[4][4] = {};
    #pragma unroll
    for (int m = 0; m < 4; ++m) ur[m][m] = 1.f;

    auto rzrow = [&](int bm, float t) {
        float ch = cosf(0.5f*t), sh = sinf(0.5f*t);
        for (int m = 0; m < 4; ++m) {
            float pi_ = (m & bm) ? sh : -sh;
            for (int j = 0; j < 4; ++j) {
                float r = ur[m][j]*ch - ui[m][j]*pi_;
                float im = ur[m][j]*pi_ + ui[m][j]*ch;
                ur[m][j] = r; ui[m][j] = im;
            }
        }
    };
    auto ryrow = [&](int bm, float t) {
        float c = cosf(0.5f*t), s = sinf(0.5f*t);
        for (int m0 = 0; m0 < 4; ++m0) {
            if (m0 & bm) continue;
            int m1 = m0 | bm;
            for (int j = 0; j < 4; ++j) {
                float r0 = ur[m0][j], i0 = ui[m0][j];
                float r1 = ur[m1][j], i1 = ui[m1][j];
                ur[m0][j] = c*r0 - s*r1; ui[m0][j] = c*i0 - s*i1;
                ur[m1][j] = s*r0 + c*r1; ui[m1][j] = s*i0 + c*i1;
            }
        }
    };
    auto swrows = [&](int x, int y) {
        for (int j = 0; j < 4; ++j) {
            float tr = ur[x][j]; ur[x][j] = ur[y][j]; ur[y][j] = tr;
            float ti = ui[x][j]; ui[x][j] = ui[y][j]; ui[y][j] = ti;
        }
    };

    const float PIH = 1.57079632679489662f;
    rzrow(2, -PIH);          // RZ on b
    swrows(2, 3);            // CNOT(b->a)
    rzrow(1, p0);            // RZ on a
    ryrow(2, p1);            // RY on b
    swrows(1, 3);            // CNOT(a->b)
    ryrow(2, p2);            // RY on b
    if (cCV[b]) { swrows(2, 3); rzrow(1, PIH); }

    for (int m = 0; m < 4; ++m)
        for (int j = 0; j < 4; ++j)
            g_U[(b*4 + m)*4 + j] = make_float2(ur[m][j], ui[m][j]);
}

// ---------------------------------------------------------------------------
// Phase 1: QCNN. One 256-thread block per sequence element; thread i owns
// amplitude i. 21 two-qubit blocks = 4x4 complex matvecs; output transposed.
// ---------------------------------------------------------------------------
__global__ __launch_bounds__(256) void qcnn_kernel(
    const float* __restrict__ sent,
    const float* __restrict__ Wf, const float* __restrict__ bfv,
    const float* __restrict__ Wi, const float* __restrict__ bi,
    const float* __restrict__ Wu, const float* __restrict__ bu,
    const float* __restrict__ Wo, const float* __restrict__ bo,
    const float* __restrict__ thf, const float* __restrict__ thi,
    const float* __restrict__ thu, const float* __restrict__ tho)
{
    __shared__ float2 sv[256];
    __shared__ float2 sU[336];
    __shared__ float  red[256];
    __shared__ float  sx[8];
    const int i = threadIdx.x;
    const int s = blockIdx.x;

    if (i < 8) sx[i] = sent[s * 8 + i];
    sU[i] = g_U[i];
    if (i < 80) sU[256 + i] = g_U[256 + i];
    __syncthreads();

    float phi = 0.f;
    #pragma unroll
    for (int q = 0; q < 8; ++q)
        if ((i >> q) & 1) phi += sx[q];
    phi *= 2.f;
    float sp, cp;
    sincosf(phi, &sp, &cp);
    sv[i] = make_float2(cp * 0.0625f, sp * 0.0625f);

    for (int blk = 0; blk < 21; ++blk) {
        const int a = cAQ[blk], bq = cBQ[blk];
        const int ma = 1 << a, mb = 1 << bq;
        const int m  = (((i >> bq) & 1) << 1) | ((i >> a) & 1);
        const int i0 = i & ~(ma | mb);
        __syncthreads();
        float2 a0 = sv[i0];
        float2 a1 = sv[i0 | ma];
        float2 a2 = sv[i0 | mb];
        float2 a3 = sv[i0 | ma | mb];
        const float2* Um = &sU[blk*16 + m*4];
        float2 U0 = Um[0], U1 = Um[1], U2 = Um[2], U3 = Um[3];
        float re = U0.x*a0.x - U0.y*a0.y + U1.x*a1.x - U1.y*a1.y
                 + U2.x*a2.x - U2.y*a2.y + U3.x*a3.x - U3.y*a3.y;
        float im = U0.x*a0.y + U0.y*a0.x + U1.x*a1.y + U1.y*a1.x
                 + U2.x*a2.y + U2.y*a2.x + U3.x*a3.y + U3.y*a3.x;
        __syncthreads();
        sv[i] = make_float2(re, im);
    }
    __syncthreads();

    float2 v = sv[i];
    red[i] = (v.x*v.x + v.y*v.y) * (((i >> 7) & 1) ? -1.f : 1.f);
    __syncthreads();
    #pragma unroll
    for (int off = 128; off > 0; off >>= 1) {
        if (i < off) red[i] += red[i + off];
        __syncthreads();
    }
    if (i < 16) {
        float e = red[0];
        int g = i >> 2, w = i & 3;
        const float* Wg  = (g == 0) ? Wf  : (g == 1) ? Wi  : (g == 2) ? Wu  : Wo;
        const float* bg  = (g == 0) ? bfv : (g == 1) ? bi  : (g == 2) ? bu  : bo;
        const float* thg = (g == 0) ? thf : (g == 1) ? thi : (g == 2) ? thu : tho;
        g_preT[i * MAXS + s] = Wg[w * 5] * e + bg[w] + thg[w];   // transposed
    }
}

// ---------------------------------------------------------------------------
// Phase 2: sequential QLSTM scan, single wave64, all-DPP cross-lane.
// 16-step super-chunks, register double-buffered: one vmcnt wait per 16
// steps with 16-step (~2400 cyc) slack >> ~900 cyc load latency.
// ---------------------------------------------------------------------------
__global__ __launch_bounds__(64) void lstm_kernel(
    const float* __restrict__ Wf, const float* __restrict__ Wi,
    const float* __restrict__ Wu, const float* __restrict__ Wo, int S)
{
    const int l   = threadIdx.x;
    const int lid = l & 15;
    const int g   = lid >> 2;
    const int w   = lid & 3;
    const float* Wg = (g == 0) ? Wf : (g == 1) ? Wi : (g == 2) ? Wu : Wo;
    // weights permuted to match DPP broadcast registers: hb_k holds h_{w^k}
    const float Wp0 = Wg[w*5 + 1 + (w    )];
    const float Wp1 = Wg[w*5 + 1 + (w ^ 1)];
    const float Wp2 = Wg[w*5 + 1 + (w ^ 2)];
    const float Wp3 = Wg[w*5 + 1 + (w ^ 3)];
    const bool  tg  = (g == 2);          // u-gate uses tanh
    const float selm = tg ? 2.f : 1.f;   // zz = z*selm ; a = selm*sg + adda
    const float adda = tg ? -1.f : 0.f;

    float hs = 0.f, hb1 = 0.f, hb2 = 0.f, hb3 = 0.f;
    float cst = 0.f;

    const float4* rowp = (const float4*)(g_preT + lid * MAXS);
    const float4 Z4 = make_float4(0.f, 0.f, 0.f, 0.f);
    const int nsc = S >> 4;              // super-chunks of 16 steps
    float4 A0 = (nsc > 0) ? rowp[0] : Z4;
    float4 A1 = (nsc > 0) ? rowp[1] : Z4;
    float4 A2 = (nsc > 0) ? rowp[2] : Z4;
    float4 A3 = (nsc > 0) ? rowp[3] : Z4;

    for (int sc = 0; sc < nsc; ++sc) {
        float4 n0 = Z4, n1 = Z4, n2 = Z4, n3 = Z4;
        if (sc + 1 < nsc) {              // prefetch next super-chunk (in flight
            n0 = rowp[4*sc + 4];         //  across all 16 steps below)
            n1 = rowp[4*sc + 5];
            n2 = rowp[4*sc + 6];
            n3 = rowp[4*sc + 7];
        }
        float pres[16];
        ((float4*)pres)[0] = A0; ((float4*)pres)[1] = A1;
        ((float4*)pres)[2] = A2; ((float4*)pres)[3] = A3;
        #pragma unroll
        for (int j = 0; j < 16; ++j) {
            // th = pre + W.h  (tree form: depth 3 from latest h)
            float t01 = fmaf(Wp0, hs, Wp1 * hb1);
            float t23 = fmaf(Wp2, hb2, fmaf(Wp3, hb3, pres[j]));
            float th  = t01 + t23;
            float d   = __cosf(th);
            // quad butterfly: z-product per (g,w)
            float v1 = dppf<QP_1032>(d);
            float pp = d * v1;
            float v2 = dppf<QP_2301>(pp);
            float z = (w == 0) ? v1 * v2
                    : (w == 1) ? pp
                    : (w == 2) ? v2 * d
                               : pp * v2;
            // activation: sigmoid (f/i/o) or tanh (u) via per-lane constants
            float sg = 1.f / (1.f + __expf(-z * selm));
            float a  = fmaf(selm, sg, adda);
            // cross-gate gather: r4 = gate g-1, r8 = g-2, r12 = g-3
            float r4  = dppf<ROR4 >(a);
            float r8  = dppf<ROR8 >(a);
            float r12 = dppf<ROR12>(a);
            float af = (g == 0) ? a : (g == 1) ? r4 : (g == 2) ? r8 : r12;
            float ai = (g == 1) ? a : (g == 2) ? r4 : (g == 3) ? r8 : r12;
            float au = (g == 2) ? a : (g == 3) ? r4 : (g == 0) ? r8 : r12;
            float ao = (g == 3) ? a : (g == 0) ? r4 : (g == 1) ? r8 : r12;
            cst = fmaf(af, cst, ai * au);
            float e2 = __expf(-2.f * cst);
            float hq = ao * (2.f / (1.f + e2) - 1.f);   // o * tanh(c)
            // broadcast within quad (parallel DPPs off hq)
            hs  = hq;
            hb1 = dppf<QP_1032>(hq);
            hb2 = dppf<QP_2301>(hq);
            hb3 = dppf<QP_3210>(hq);
            if (l == 0)
                *(float4*)(g_hs + 4 * (sc * 16 + j)) = make_float4(hs, hb1, hb2, hb3);
        }
        A0 = n0; A1 = n1; A2 = n2; A3 = n3;   // wait lands here: 16-step slack
    }
    // scalar tail for S % 16 != 0 (S=2048: no-op)
    for (int t = nsc * 16; t < S; ++t) {
        float cur = g_preT[lid * MAXS + t];
        float t01 = fmaf(Wp0, hs, Wp1 * hb1);
        float t23 = fmaf(Wp2, hb2, fmaf(Wp3, hb3, cur));
        float th  = t01 + t23;
        float d   = __cosf(th);
        float v1 = dppf<QP_1032>(d);
        float pp = d * v1;
        float v2 = dppf<QP_2301>(pp);
        float z = (w == 0) ? v1 * v2 : (w == 1) ? pp : (w == 2) ? v2 * d : pp * v2;
        float sg = 1.f / (1.f + __expf(-z * selm));
        float a  = fmaf(selm, sg, adda);
        float r4  = dppf<ROR4 >(a);
        float r8  = dppf<ROR8 >(a);
        float r12 = dppf<ROR12>(a);
        float af = (g == 0) ? a : (g == 1) ? r4 : (g == 2) ? r8 : r12;
        float ai = (g == 1) ? a : (g == 2) ? r4 : (g == 3) ? r8 : r12;
        float au = (g == 2) ? a : (g == 3) ? r4 : (g == 0) ? r8 : r12;
        float ao = (g == 3) ? a : (g == 0) ? r4 : (g == 1) ? r8 : r12;
        cst = fmaf(af, cst, ai * au);
        float e2 = __expf(-2.f * cst);
        float hq = ao * (2.f / (1.f + e2) - 1.f);
        hs  = hq;
        hb1 = dppf<QP_1032>(hq);
        hb2 = dppf<QP_2301>(hq);
        hb3 = dppf<QP_3210>(hq);
        if (l == 0)
            *(float4*)(g_hs + 4 * t) = make_float4(hs, hb1, hb2, hb3);
    }
}

// ---------------------------------------------------------------------------
// Phase 3: logits = hs @ Wt^T + bt over 32 tags; log_softmax over 32. fp32 out.
// ---------------------------------------------------------------------------
__global__ __launch_bounds__(256) void head_kernel(
    const float* __restrict__ Wt, const float* __restrict__ bt,
    float* __restrict__ out, int S)
{
    __shared__ float sW[128];   // (32 tags, 4 hid) row-major
    __shared__ float sb[32];
    const int tid = threadIdx.x;
    if (tid < 128) sW[tid] = Wt[tid];
    if (tid < 32)  sb[tid] = bt[tid];
    __syncthreads();

    const int t = blockIdx.x * blockDim.x + tid;
    if (t >= S) return;
    const float h0 = g_hs[4*t+0], h1 = g_hs[4*t+1];
    const float h2 = g_hs[4*t+2], h3 = g_hs[4*t+3];
    float lg[32];
    float m = -1e30f;
    #pragma unroll
    for (int j = 0; j < 32; ++j) {
        lg[j] = sW[4*j+0]*h0 + sW[4*j+1]*h1 + sW[4*j+2]*h2 + sW[4*j+3]*h3 + sb[j];
        m = fmaxf(m, lg[j]);
    }
    float se = 0.f;
    #pragma unroll
    for (int j = 0; j < 32; ++j) se += __expf(lg[j] - m);
    float lse = m + __logf(se);
    #pragma unroll
    for (int j = 0; j < 32; ++j) out[32*t+j] = lg[j] - lse;
}

extern "C" void kernel_launch(void* const* d_in, const int* in_sizes, int n_in,
                              void* d_out, int out_size, void* d_ws, size_t ws_size,
                              hipStream_t stream)
{
    const float* sent = (const float*)d_in[0];
    const float* wq   = (const float*)d_in[1];
    const float* Wf   = (const float*)d_in[2];  const float* bfv = (const float*)d_in[3];
    const float* Wi   = (const float*)d_in[4];  const float* bi  = (const float*)d_in[5];
    const float* Wu   = (const float*)d_in[6];  const float* bu  = (const float*)d_in[7];
    const float* Wo   = (const float*)d_in[8];  const float* bo  = (const float*)d_in[9];
    const float* thf  = (const float*)d_in[10]; const float* thi = (const float*)d_in[11];
    const float* thu  = (const float*)d_in[12]; const float* tho = (const float*)d_in[13];
    const float* Wt   = (const float*)d_in[14]; const float* bt  = (const float*)d_in[15];

    int S = in_sizes[0] / 8;                // 2048 (B = 1)
    if (S > MAXS) S = MAXS;
    float* outp = (float*)d_out;

    prep_kernel<<<1, 32, 0, stream>>>(wq);
    qcnn_kernel<<<S, 256, 0, stream>>>(sent, Wf, bfv, Wi, bi, Wu, bu, Wo, bo,
                                       thf, thi, thu, tho);
    lstm_kernel<<<1, 64, 0, stream>>>(Wf, Wi, Wu, Wo, S);
    head_kernel<<<(S + 255) / 256, 256, 0, stream>>>(Wt, bt, outp, S);
}

// Round 11
// 141.946 us; speedup vs baseline: 7.1539x; 4.1932x over previous
//
#include <hip/hip_runtime.h>
#include <math.h>

// Dtype map (pinned R0-R7): all inputs fp32, output fp32. Internal fp32.
// R10 post-mortem: deep prefetch was NEUTRAL => the scan runs at its serial
// VALU dependency-chain rate; only breaking serialization helps. R11: the
// recurrence is contracting (z = product of cosines in [-1,1] => forget gate
// f in [0.269, 0.731]; init-condition error decays <= 0.731^k), so split the
// scan into 64 segments of L=32 with W=64 warmup steps from (h,c)=(0,0).
// 64 independent waves, <=96 serial steps each vs 2048 (block 0: exact, no
// warmup). Segmentation error ~1e-8. Step math unchanged (all-DPP, bit-exact
// in R8-R10).

#define MAXS 2048
#define SEG  32
#define WARM 64

__device__ __align__(16) float g_preT[16 * MAXS]; // [lid][t] gate pre-activations
__device__ __align__(16) float g_hs [MAXS * 4];   // per-step hidden state
__device__ float2 g_U[21 * 16];                   // 21 blocks x 4x4 complex

// DPP helper: ctrl must be a compile-time constant.
template <int CTRL>
__device__ __forceinline__ float dppf(float x) {
    return __int_as_float(__builtin_amdgcn_update_dpp(
        0, __float_as_int(x), CTRL, 0xF, 0xF, true));
}
// quad_perm encodings                 // out quad-lane k = in lane p[k]
#define QP_1032 0xB1                   // [1,0,3,2]  (swap pairs)
#define QP_2301 0x4E                   // [2,3,0,1]  (swap pair-groups)
#define QP_3210 0x1B                   // [3,2,1,0]  (reverse)
#define ROR4  0x124                    // out[l] = in[(l-4)&15]
#define ROR8  0x128
#define ROR12 0x12C

// Shared wiring tables
__constant__ int  cAQ[21] = {0,2,4,6,1,3,5,7, 0,1,2,3, 0,2,1,3, 0,1, 0,1, 0};
__constant__ int  cBQ[21] = {1,3,5,7,2,4,6,0, 4,5,6,7, 1,3,2,0, 2,3, 1,0, 1};
__constant__ int  cCV[21] = {1,1,1,1,1,1,1,1, 0,0,0,0, 1,1,1,1, 0,0, 1,1, 0};

// ---------------------------------------------------------------------------
// Phase 0: compose each conv/pool block's 4x4 complex unitary ONCE.
// ---------------------------------------------------------------------------
__global__ void prep_kernel(const float* __restrict__ wpar) {
    const int b = threadIdx.x;
    if (b >= 21) return;
    const float p0 = wpar[3*b], p1 = wpar[3*b+1], p2 = wpar[3*b+2];
    float ur[4][4] = {}, ui[4][4] = {};
    #pragma unroll
    for (int m = 0; m < 4; ++m) ur[m][m] = 1.f;

    auto rzrow = [&](int bm, float t) {
        float ch = cosf(0.5f*t), sh = sinf(0.5f*t);
        for (int m = 0; m < 4; ++m) {
            float pi_ = (m & bm) ? sh : -sh;
            for (int j = 0; j < 4; ++j) {
                float r = ur[m][j]*ch - ui[m][j]*pi_;
                float im = ur[m][j]*pi_ + ui[m][j]*ch;
                ur[m][j] = r; ui[m][j] = im;
            }
        }
    };
    auto ryrow = [&](int bm, float t) {
        float c = cosf(0.5f*t), s = sinf(0.5f*t);
        for (int m0 = 0; m0 < 4; ++m0) {
            if (m0 & bm) continue;
            int m1 = m0 | bm;
            for (int j = 0; j < 4; ++j) {
                float r0 = ur[m0][j], i0 = ui[m0][j];
                float r1 = ur[m1][j], i1 = ui[m1][j];
                ur[m0][j] = c*r0 - s*r1; ui[m0][j] = c*i0 - s*i1;
                ur[m1][j] = s*r0 + c*r1; ui[m1][j] = s*i0 + c*i1;
            }
        }
    };
    auto swrows = [&](int x, int y) {
        for (int j = 0; j < 4; ++j) {
            float tr = ur[x][j]; ur[x][j] = ur[y][j]; ur[y][j] = tr;
            float ti = ui[x][j]; ui[x][j] = ui[y][j]; ui[y][j] = ti;
        }
    };

    const float PIH = 1.57079632679489662f;
    rzrow(2, -PIH);          // RZ on b
    swrows(2, 3);            // CNOT(b->a)
    rzrow(1, p0);            // RZ on a
    ryrow(2, p1);            // RY on b
    swrows(1, 3);            // CNOT(a->b)
    ryrow(2, p2);            // RY on b
    if (cCV[b]) { swrows(2, 3); rzrow(1, PIH); }

    for (int m = 0; m < 4; ++m)
        for (int j = 0; j < 4; ++j)
            g_U[(b*4 + m)*4 + j] = make_float2(ur[m][j], ui[m][j]);
}

// ---------------------------------------------------------------------------
// Phase 1: QCNN. One 256-thread block per sequence element; thread i owns
// amplitude i. 21 two-qubit blocks = 4x4 complex matvecs; output transposed.
// ---------------------------------------------------------------------------
__global__ __launch_bounds__(256) void qcnn_kernel(
    const float* __restrict__ sent,
    const float* __restrict__ Wf, const float* __restrict__ bfv,
    const float* __restrict__ Wi, const float* __restrict__ bi,
    const float* __restrict__ Wu, const float* __restrict__ bu,
    const float* __restrict__ Wo, const float* __restrict__ bo,
    const float* __restrict__ thf, const float* __restrict__ thi,
    const float* __restrict__ thu, const float* __restrict__ tho)
{
    __shared__ float2 sv[256];
    __shared__ float2 sU[336];
    __shared__ float  red[256];
    __shared__ float  sx[8];
    const int i = threadIdx.x;
    const int s = blockIdx.x;

    if (i < 8) sx[i] = sent[s * 8 + i];
    sU[i] = g_U[i];
    if (i < 80) sU[256 + i] = g_U[256 + i];
    __syncthreads();

    float phi = 0.f;
    #pragma unroll
    for (int q = 0; q < 8; ++q)
        if ((i >> q) & 1) phi += sx[q];
    phi *= 2.f;
    float sp, cp;
    sincosf(phi, &sp, &cp);
    sv[i] = make_float2(cp * 0.0625f, sp * 0.0625f);

    for (int blk = 0; blk < 21; ++blk) {
        const int a = cAQ[blk], bq = cBQ[blk];
        const int ma = 1 << a, mb = 1 << bq;
        const int m  = (((i >> bq) & 1) << 1) | ((i >> a) & 1);
        const int i0 = i & ~(ma | mb);
        __syncthreads();
        float2 a0 = sv[i0];
        float2 a1 = sv[i0 | ma];
        float2 a2 = sv[i0 | mb];
        float2 a3 = sv[i0 | ma | mb];
        const float2* Um = &sU[blk*16 + m*4];
        float2 U0 = Um[0], U1 = Um[1], U2 = Um[2], U3 = Um[3];
        float re = U0.x*a0.x - U0.y*a0.y + U1.x*a1.x - U1.y*a1.y
                 + U2.x*a2.x - U2.y*a2.y + U3.x*a3.x - U3.y*a3.y;
        float im = U0.x*a0.y + U0.y*a0.x + U1.x*a1.y + U1.y*a1.x
                 + U2.x*a2.y + U2.y*a2.x + U3.x*a3.y + U3.y*a3.x;
        __syncthreads();
        sv[i] = make_float2(re, im);
    }
    __syncthreads();

    float2 v = sv[i];
    red[i] = (v.x*v.x + v.y*v.y) * (((i >> 7) & 1) ? -1.f : 1.f);
    __syncthreads();
    #pragma unroll
    for (int off = 128; off > 0; off >>= 1) {
        if (i < off) red[i] += red[i + off];
        __syncthreads();
    }
    if (i < 16) {
        float e = red[0];
        int g = i >> 2, w = i & 3;
        const float* Wg  = (g == 0) ? Wf  : (g == 1) ? Wi  : (g == 2) ? Wu  : Wo;
        const float* bg  = (g == 0) ? bfv : (g == 1) ? bi  : (g == 2) ? bu  : bo;
        const float* thg = (g == 0) ? thf : (g == 1) ? thi : (g == 2) ? thu : tho;
        g_preT[i * MAXS + s] = Wg[w * 5] * e + bg[w] + thg[w];   // transposed
    }
}

// ---------------------------------------------------------------------------
// Phase 2: SEGMENTED QLSTM scan. Block b owns t in [b*SEG, (b+1)*SEG), with
// WARM warmup steps from (h,c)=(0,0) starting at t0 = max(0, b*SEG - WARM)
// (block 0: exact init). Contraction (f <= 0.731) kills the init error by
// ~1e-8 over 64 steps. Per-wave step math = R10's all-DPP chain, unchanged.
// ---------------------------------------------------------------------------
__global__ __launch_bounds__(64) void lstm_kernel(
    const float* __restrict__ Wf, const float* __restrict__ Wi,
    const float* __restrict__ Wu, const float* __restrict__ Wo, int S)
{
    const int b      = blockIdx.x;
    const int tstart = b * SEG;
    if (tstart >= S) return;
    const int tend = (tstart + SEG < S) ? tstart + SEG : S;
    const int t0   = (tstart >= WARM) ? tstart - WARM : 0;

    const int l   = threadIdx.x;
    const int lid = l & 15;
    const int g   = lid >> 2;
    const int w   = lid & 3;
    const float* Wg = (g == 0) ? Wf : (g == 1) ? Wi : (g == 2) ? Wu : Wo;
    // weights permuted to match DPP broadcast registers: hb_k holds h_{w^k}
    const float Wp0 = Wg[w*5 + 1 + (w    )];
    const float Wp1 = Wg[w*5 + 1 + (w ^ 1)];
    const float Wp2 = Wg[w*5 + 1 + (w ^ 2)];
    const float Wp3 = Wg[w*5 + 1 + (w ^ 3)];
    const bool  tg  = (g == 2);          // u-gate uses tanh
    const float selm = tg ? 2.f : 1.f;   // zz = z*selm ; a = selm*sg + adda
    const float adda = tg ? -1.f : 0.f;

    float hs = 0.f, hb1 = 0.f, hb2 = 0.f, hb3 = 0.f;
    float cst = 0.f;

    // one step of the recurrence (all-DPP); returns nothing, updates state
    auto step = [&](float pre, int t) {
        float t01 = fmaf(Wp0, hs, Wp1 * hb1);
        float t23 = fmaf(Wp2, hb2, fmaf(Wp3, hb3, pre));
        float th  = t01 + t23;
        float d   = __cosf(th);
        float v1 = dppf<QP_1032>(d);
        float pp = d * v1;
        float v2 = dppf<QP_2301>(pp);
        float z = (w == 0) ? v1 * v2
                : (w == 1) ? pp
                : (w == 2) ? v2 * d
                           : pp * v2;
        float sg = 1.f / (1.f + __expf(-z * selm));
        float a  = fmaf(selm, sg, adda);
        float r4  = dppf<ROR4 >(a);
        float r8  = dppf<ROR8 >(a);
        float r12 = dppf<ROR12>(a);
        float af = (g == 0) ? a : (g == 1) ? r4 : (g == 2) ? r8 : r12;
        float ai = (g == 1) ? a : (g == 2) ? r4 : (g == 3) ? r8 : r12;
        float au = (g == 2) ? a : (g == 3) ? r4 : (g == 0) ? r8 : r12;
        float ao = (g == 3) ? a : (g == 0) ? r4 : (g == 1) ? r8 : r12;
        cst = fmaf(af, cst, ai * au);
        float e2 = __expf(-2.f * cst);
        float hq = ao * (2.f / (1.f + e2) - 1.f);   // o * tanh(c)
        hs  = hq;
        hb1 = dppf<QP_1032>(hq);
        hb2 = dppf<QP_2301>(hq);
        hb3 = dppf<QP_3210>(hq);
        if (l == 0 && t >= tstart)
            *(float4*)(g_hs + 4 * t) = make_float4(hs, hb1, hb2, hb3);
    };

    // 16-step chunks, register double-buffered (t0 is a multiple of 32 or 0,
    // so float4-aligned). Scalar tail covers tend not divisible by 16.
    const float4* rowp = (const float4*)(g_preT + lid * MAXS + t0);
    const float4  Z4 = make_float4(0.f, 0.f, 0.f, 0.f);
    const int nsteps = tend - t0;
    const int nsc = nsteps >> 4;
    float4 A0 = (nsc > 0) ? rowp[0] : Z4;
    float4 A1 = (nsc > 0) ? rowp[1] : Z4;
    float4 A2 = (nsc > 0) ? rowp[2] : Z4;
    float4 A3 = (nsc > 0) ? rowp[3] : Z4;

    for (int sc = 0; sc < nsc; ++sc) {
        float4 n0 = Z4, n1 = Z4, n2 = Z4, n3 = Z4;
        if (sc + 1 < nsc) {
            n0 = rowp[4*sc + 4];
            n1 = rowp[4*sc + 5];
            n2 = rowp[4*sc + 6];
            n3 = rowp[4*sc + 7];
        }
        float pres[16];
        ((float4*)pres)[0] = A0; ((float4*)pres)[1] = A1;
        ((float4*)pres)[2] = A2; ((float4*)pres)[3] = A3;
        #pragma unroll
        for (int j = 0; j < 16; ++j)
            step(pres[j], t0 + sc * 16 + j);
        A0 = n0; A1 = n1; A2 = n2; A3 = n3;
    }
    for (int t = t0 + nsc * 16; t < tend; ++t)
        step(g_preT[lid * MAXS + t], t);
}

// ---------------------------------------------------------------------------
// Phase 3: logits = hs @ Wt^T + bt over 32 tags; log_softmax over 32. fp32 out.
// ---------------------------------------------------------------------------
__global__ __launch_bounds__(256) void head_kernel(
    const float* __restrict__ Wt, const float* __restrict__ bt,
    float* __restrict__ out, int S)
{
    __shared__ float sW[128];   // (32 tags, 4 hid) row-major
    __shared__ float sb[32];
    const int tid = threadIdx.x;
    if (tid < 128) sW[tid] = Wt[tid];
    if (tid < 32)  sb[tid] = bt[tid];
    __syncthreads();

    const int t = blockIdx.x * blockDim.x + tid;
    if (t >= S) return;
    const float h0 = g_hs[4*t+0], h1 = g_hs[4*t+1];
    const float h2 = g_hs[4*t+2], h3 = g_hs[4*t+3];
    float lg[32];
    float m = -1e30f;
    #pragma unroll
    for (int j = 0; j < 32; ++j) {
        lg[j] = sW[4*j+0]*h0 + sW[4*j+1]*h1 + sW[4*j+2]*h2 + sW[4*j+3]*h3 + sb[j];
        m = fmaxf(m, lg[j]);
    }
    float se = 0.f;
    #pragma unroll
    for (int j = 0; j < 32; ++j) se += __expf(lg[j] - m);
    float lse = m + __logf(se);
    #pragma unroll
    for (int j = 0; j < 32; ++j) out[32*t+j] = lg[j] - lse;
}

extern "C" void kernel_launch(void* const* d_in, const int* in_sizes, int n_in,
                              void* d_out, int out_size, void* d_ws, size_t ws_size,
                              hipStream_t stream)
{
    const float* sent = (const float*)d_in[0];
    const float* wq   = (const float*)d_in[1];
    const float* Wf   = (const float*)d_in[2];  const float* bfv = (const float*)d_in[3];
    const float* Wi   = (const float*)d_in[4];  const float* bi  = (const float*)d_in[5];
    const float* Wu   = (const float*)d_in[6];  const float* bu  = (const float*)d_in[7];
    const float* Wo   = (const float*)d_in[8];  const float* bo  = (const float*)d_in[9];
    const float* thf  = (const float*)d_in[10]; const float* thi = (const float*)d_in[11];
    const float* thu  = (const float*)d_in[12]; const float* tho = (const float*)d_in[13];
    const float* Wt   = (const float*)d_in[14]; const float* bt  = (const float*)d_in[15];

    int S = in_sizes[0] / 8;                // 2048 (B = 1)
    if (S > MAXS) S = MAXS;
    float* outp = (float*)d_out;
    const int nseg = (S + SEG - 1) / SEG;   // 64 segments

    prep_kernel<<<1, 32, 0, stream>>>(wq);
    qcnn_kernel<<<S, 256, 0, stream>>>(sent, Wf, bfv, Wi, bi, Wu, bu, Wo, bo,
                                       thf, thi, thu, tho);
    lstm_kernel<<<nseg, 64, 0, stream>>>(Wf, Wi, Wu, Wo, S);
    head_kernel<<<(S + 255) / 256, 256, 0, stream>>>(Wt, bt, outp, S);
}

// Round 12
// 116.797 us; speedup vs baseline: 8.6943x; 1.2153x over previous
//
#include <hip/hip_runtime.h>
#include <math.h>

// Dtype map (pinned R0-R7): all inputs fp32, output fp32. Internal fp32.
// R11: segmentation validated (absmax 0.0) — contraction is real (f<=0.731
// guaranteed since z = product of cosines in [-1,1]). R12:
//  - lstm: SEG 32->16, WARM 64->32 (48 serial steps, 128 blocks)
//  - qcnn: wave-synchronous rewrite — one wave per state, 4 amps/lane,
//    LDS exchange with NO __syncthreads (per-wave DS ordering + wave_barrier
//    compiler fences); init + final reduction in registers (group (0,1)).
//  - prep folded into qcnn (wave 0 per block), one less launch.

#define MAXS 2048
#define SEG  16
#define WARM 32

__device__ __align__(16) float g_preT[16 * MAXS]; // [lid][t] gate pre-activations
__device__ __align__(16) float g_hs [MAXS * 4];   // per-step hidden state

// DPP helper: ctrl must be a compile-time constant.
template <int CTRL>
__device__ __forceinline__ float dppf(float x) {
    return __int_as_float(__builtin_amdgcn_update_dpp(
        0, __float_as_int(x), CTRL, 0xF, 0xF, true));
}
// quad_perm encodings                 // out quad-lane k = in lane p[k]
#define QP_1032 0xB1                   // [1,0,3,2]  (swap pairs)
#define QP_2301 0x4E                   // [2,3,0,1]  (swap pair-groups)
#define QP_3210 0x1B                   // [3,2,1,0]  (reverse)
#define ROR4  0x124                    // out[l] = in[(l-4)&15]
#define ROR8  0x128
#define ROR12 0x12C

// Block wiring (CONV1, POOL1, CONV2, POOL2, CONV3, POOL3)
__constant__ int  cAQ[21] = {0,2,4,6,1,3,5,7, 0,1,2,3, 0,2,1,3, 0,1, 0,1, 0};
__constant__ int  cBQ[21] = {1,3,5,7,2,4,6,0, 4,5,6,7, 1,3,2,0, 2,3, 1,0, 1};
__constant__ int  cCV[21] = {1,1,1,1,1,1,1,1, 0,0,0,0, 1,1,1,1, 0,0, 1,1, 0};

__device__ __forceinline__ float2 cmulacc(float2 acc, float2 u, float2 a) {
    acc.x = fmaf(u.x, a.x, fmaf(-u.y, a.y, acc.x));
    acc.y = fmaf(u.x, a.y, fmaf( u.y, a.x, acc.y));
    return acc;
}

// ---------------------------------------------------------------------------
// Phase 1: QCNN, wave-synchronous. Block = 256 threads = 4 waves = 4 states.
// Wave w owns state s = blockIdx*4 + w; lane L owns the 4 amps of one
// (a,b)-subspace group. Exchanges go through a per-wave 2 KB LDS slice —
// per-wave DS ordering makes barriers unnecessary (wave_barrier = compiler
// fence only). Wave 0 lanes 0-20 first compose the 21 4x4 block unitaries.
// ---------------------------------------------------------------------------
__global__ __launch_bounds__(256) void qcnn_kernel(
    const float* __restrict__ sent, const float* __restrict__ wpar,
    const float* __restrict__ Wf, const float* __restrict__ bfv,
    const float* __restrict__ Wi, const float* __restrict__ bi,
    const float* __restrict__ Wu, const float* __restrict__ bu,
    const float* __restrict__ Wo, const float* __restrict__ bo,
    const float* __restrict__ thf, const float* __restrict__ thi,
    const float* __restrict__ thu, const float* __restrict__ tho, int S)
{
    __shared__ float2 sU[336];          // 21 x 4x4 complex
    __shared__ float2 sv[4 * 256];      // 4 waves x 256 amps
    const int tid = threadIdx.x;
    const int wid = tid >> 6;
    const int L   = tid & 63;

    // ---- compose block unitaries (threads 0..20 = wave 0) ----
    if (tid < 21) {
        const int b = tid;
        const float p0 = wpar[3*b], p1 = wpar[3*b+1], p2 = wpar[3*b+2];
        float ur[4][4] = {}, ui[4][4] = {};
        #pragma unroll
        for (int m = 0; m < 4; ++m) ur[m][m] = 1.f;
        auto rzrow = [&](int bm, float t) {
            float ch = cosf(0.5f*t), sh = sinf(0.5f*t);
            for (int m = 0; m < 4; ++m) {
                float pi_ = (m & bm) ? sh : -sh;
                for (int j = 0; j < 4; ++j) {
                    float r = ur[m][j]*ch - ui[m][j]*pi_;
                    float im = ur[m][j]*pi_ + ui[m][j]*ch;
                    ur[m][j] = r; ui[m][j] = im;
                }
            }
        };
        auto ryrow = [&](int bm, float t) {
            float c = cosf(0.5f*t), s = sinf(0.5f*t);
            for (int m0 = 0; m0 < 4; ++m0) {
                if (m0 & bm) continue;
                int m1 = m0 | bm;
                for (int j = 0; j < 4; ++j) {
                    float r0 = ur[m0][j], i0 = ui[m0][j];
                    float r1 = ur[m1][j], i1 = ui[m1][j];
                    ur[m0][j] = c*r0 - s*r1; ui[m0][j] = c*i0 - s*i1;
                    ur[m1][j] = s*r0 + c*r1; ui[m1][j] = s*i0 + c*i1;
                }
            }
        };
        auto swrows = [&](int x, int y) {
            for (int j = 0; j < 4; ++j) {
                float tr = ur[x][j]; ur[x][j] = ur[y][j]; ur[y][j] = tr;
                float ti = ui[x][j]; ui[x][j] = ui[y][j]; ui[y][j] = ti;
            }
        };
        const float PIH = 1.57079632679489662f;
        rzrow(2, -PIH); swrows(2, 3); rzrow(1, p0); ryrow(2, p1);
        swrows(1, 3);   ryrow(2, p2);
        if (cCV[b]) { swrows(2, 3); rzrow(1, PIH); }
        for (int m = 0; m < 4; ++m)
            for (int j = 0; j < 4; ++j)
                sU[(b*4 + m)*4 + j] = make_float2(ur[m][j], ui[m][j]);
    }
    __syncthreads();                    // the ONLY block-wide barrier

    int s = blockIdx.x * 4 + wid;
    const bool live = (s < S);
    if (!live) s = S - 1;               // clamp reads; writes guarded below

    float xs[8];
    #pragma unroll
    for (int q = 0; q < 8; ++q) xs[q] = sent[s * 8 + q];

    // init amps for group (0,1): j = L*4 + k ; amp = (1/16) e^{i 2 phi}
    float base = 0.f;
    #pragma unroll
    for (int q = 2; q < 8; ++q)
        if ((L >> (q - 2)) & 1) base += xs[q];
    base *= 2.f;
    float2 r[4];
    #pragma unroll
    for (int k = 0; k < 4; ++k) {
        float ph = base;
        if (k & 1) ph += 2.f * xs[0];
        if (k & 2) ph += 2.f * xs[1];
        float sp, cp;
        sincosf(ph, &sp, &cp);
        r[k] = make_float2(cp * 0.0625f, sp * 0.0625f);
    }

    float2* mysv = sv + wid * 256;
    int curi0 = L * 4, curma = 1, curmb = 2;   // current group = qubits (0,1)

    #pragma unroll
    for (int blk = 0; blk < 21; ++blk) {
        // 4x4 complex matvec in registers
        float2 o[4];
        #pragma unroll
        for (int m = 0; m < 4; ++m) {
            float2 acc = make_float2(0.f, 0.f);
            #pragma unroll
            for (int j = 0; j < 4; ++j)
                acc = cmulacc(acc, sU[blk*16 + m*4 + j], r[j]);
            o[m] = acc;
        }
        #pragma unroll
        for (int m = 0; m < 4; ++m) r[m] = o[m];

        if (blk < 20) {
            // exchange: write current group, read next block's group
            mysv[curi0         ] = r[0];
            mysv[curi0 + curma ] = r[1];
            mysv[curi0 + curmb ] = r[2];
            mysv[curi0 + curma + curmb] = r[3];
            __builtin_amdgcn_wave_barrier();
            const int a2 = cAQ[blk+1], b2 = cBQ[blk+1];
            const int ma = 1 << a2, mb = 1 << b2;
            const int p  = (a2 < b2) ? a2 : b2;
            const int q  = (a2 < b2) ? b2 : a2;
            const int m1 = (1 << p) - 1;
            const int m2 = (1 << (q - 1)) - 1;
            const int i0 = (L & m1) | ((L & (m2 ^ m1)) << 1) | ((L & ~m2) << 2);
            r[0] = mysv[i0];
            r[1] = mysv[i0 + ma];
            r[2] = mysv[i0 + mb];
            r[3] = mysv[i0 + ma + mb];
            __builtin_amdgcn_wave_barrier();
            curi0 = i0; curma = ma; curmb = mb;
        }
    }

    // final group = (0,1): j = L*4+k, bit7(j) = L>>5 -> sign per lane
    float pr = fmaf(r[0].x, r[0].x, r[0].y * r[0].y)
             + fmaf(r[1].x, r[1].x, r[1].y * r[1].y)
             + fmaf(r[2].x, r[2].x, r[2].y * r[2].y)
             + fmaf(r[3].x, r[3].x, r[3].y * r[3].y);
    if (L >= 32) pr = -pr;
    #pragma unroll
    for (int off = 32; off > 0; off >>= 1)
        pr += __shfl_xor(pr, off, 64);

    if (live && L < 16) {
        const int g = L >> 2, w = L & 3;
        const float* Wg  = (g == 0) ? Wf  : (g == 1) ? Wi  : (g == 2) ? Wu  : Wo;
        const float* bg  = (g == 0) ? bfv : (g == 1) ? bi  : (g == 2) ? bu  : bo;
        const float* thg = (g == 0) ? thf : (g == 1) ? thi : (g == 2) ? thu : tho;
        g_preT[L * MAXS + s] = Wg[w * 5] * pr + bg[w] + thg[w];
    }
}

// ---------------------------------------------------------------------------
// Phase 2: SEGMENTED QLSTM scan. Block b owns t in [b*SEG, b*SEG+SEG), with
// WARM warmup steps from (h,c)=(0,0) (block 0 exact). f <= sigma(1) = 0.731
// guaranteed => init error attenuated by <= 0.731^WARM ~ 4e-5. All-DPP step.
// ---------------------------------------------------------------------------
__global__ __launch_bounds__(64) void lstm_kernel(
    const float* __restrict__ Wf, const float* __restrict__ Wi,
    const float* __restrict__ Wu, const float* __restrict__ Wo, int S)
{
    const int b      = blockIdx.x;
    const int tstart = b * SEG;
    if (tstart >= S) return;
    const int tend = (tstart + SEG < S) ? tstart + SEG : S;
    const int t0   = (tstart >= WARM) ? tstart - WARM : 0;

    const int l   = threadIdx.x;
    const int lid = l & 15;
    const int g   = lid >> 2;
    const int w   = lid & 3;
    const float* Wg = (g == 0) ? Wf : (g == 1) ? Wi : (g == 2) ? Wu : Wo;
    // weights permuted to match DPP broadcast registers: hb_k holds h_{w^k}
    const float Wp0 = Wg[w*5 + 1 + (w    )];
    const float Wp1 = Wg[w*5 + 1 + (w ^ 1)];
    const float Wp2 = Wg[w*5 + 1 + (w ^ 2)];
    const float Wp3 = Wg[w*5 + 1 + (w ^ 3)];
    const bool  tg  = (g == 2);          // u-gate uses tanh
    const float selm = tg ? 2.f : 1.f;
    const float adda = tg ? -1.f : 0.f;

    float hs = 0.f, hb1 = 0.f, hb2 = 0.f, hb3 = 0.f;
    float cst = 0.f;

    auto step = [&](float pre, int t) {
        float t01 = fmaf(Wp0, hs, Wp1 * hb1);
        float t23 = fmaf(Wp2, hb2, fmaf(Wp3, hb3, pre));
        float th  = t01 + t23;
        float d   = __cosf(th);
        float v1 = dppf<QP_1032>(d);
        float pp = d * v1;
        float v2 = dppf<QP_2301>(pp);
        float z = (w == 0) ? v1 * v2
                : (w == 1) ? pp
                : (w == 2) ? v2 * d
                           : pp * v2;
        float sg = 1.f / (1.f + __expf(-z * selm));
        float a  = fmaf(selm, sg, adda);
        float r4  = dppf<ROR4 >(a);
        float r8  = dppf<ROR8 >(a);
        float r12 = dppf<ROR12>(a);
        float af = (g == 0) ? a : (g == 1) ? r4 : (g == 2) ? r8 : r12;
        float ai = (g == 1) ? a : (g == 2) ? r4 : (g == 3) ? r8 : r12;
        float au = (g == 2) ? a : (g == 3) ? r4 : (g == 0) ? r8 : r12;
        float ao = (g == 3) ? a : (g == 0) ? r4 : (g == 1) ? r8 : r12;
        cst = fmaf(af, cst, ai * au);
        float e2 = __expf(-2.f * cst);
        float hq = ao * (2.f / (1.f + e2) - 1.f);   // o * tanh(c)
        hs  = hq;
        hb1 = dppf<QP_1032>(hq);
        hb2 = dppf<QP_2301>(hq);
        hb3 = dppf<QP_3210>(hq);
        if (l == 0 && t >= tstart)
            *(float4*)(g_hs + 4 * t) = make_float4(hs, hb1, hb2, hb3);
    };

    // 16-step chunks, register double-buffered (t0 multiple of 16 -> aligned)
    const float4* rowp = (const float4*)(g_preT + lid * MAXS + t0);
    const float4  Z4 = make_float4(0.f, 0.f, 0.f, 0.f);
    const int nsteps = tend - t0;
    const int nsc = nsteps >> 4;
    float4 A0 = (nsc > 0) ? rowp[0] : Z4;
    float4 A1 = (nsc > 0) ? rowp[1] : Z4;
    float4 A2 = (nsc > 0) ? rowp[2] : Z4;
    float4 A3 = (nsc > 0) ? rowp[3] : Z4;

    for (int sc = 0; sc < nsc; ++sc) {
        float4 n0 = Z4, n1 = Z4, n2 = Z4, n3 = Z4;
        if (sc + 1 < nsc) {
            n0 = rowp[4*sc + 4];
            n1 = rowp[4*sc + 5];
            n2 = rowp[4*sc + 6];
            n3 = rowp[4*sc + 7];
        }
        float pres[16];
        ((float4*)pres)[0] = A0; ((float4*)pres)[1] = A1;
        ((float4*)pres)[2] = A2; ((float4*)pres)[3] = A3;
        #pragma unroll
        for (int j = 0; j < 16; ++j)
            step(pres[j], t0 + sc * 16 + j);
        A0 = n0; A1 = n1; A2 = n2; A3 = n3;
    }
    for (int t = t0 + nsc * 16; t < tend; ++t)
        step(g_preT[lid * MAXS + t], t);
}

// ---------------------------------------------------------------------------
// Phase 3: logits = hs @ Wt^T + bt over 32 tags; log_softmax over 32. fp32 out.
// ---------------------------------------------------------------------------
__global__ __launch_bounds__(256) void head_kernel(
    const float* __restrict__ Wt, const float* __restrict__ bt,
    float* __restrict__ out, int S)
{
    __shared__ float sW[128];   // (32 tags, 4 hid) row-major
    __shared__ float sb[32];
    const int tid = threadIdx.x;
    if (tid < 128) sW[tid] = Wt[tid];
    if (tid < 32)  sb[tid] = bt[tid];
    __syncthreads();

    const int t = blockIdx.x * blockDim.x + tid;
    if (t >= S) return;
    const float h0 = g_hs[4*t+0], h1 = g_hs[4*t+1];
    const float h2 = g_hs[4*t+2], h3 = g_hs[4*t+3];
    float lg[32];
    float m = -1e30f;
    #pragma unroll
    for (int j = 0; j < 32; ++j) {
        lg[j] = sW[4*j+0]*h0 + sW[4*j+1]*h1 + sW[4*j+2]*h2 + sW[4*j+3]*h3 + sb[j];
        m = fmaxf(m, lg[j]);
    }
    float se = 0.f;
    #pragma unroll
    for (int j = 0; j < 32; ++j) se += __expf(lg[j] - m);
    float lse = m + __logf(se);
    #pragma unroll
    for (int j = 0; j < 32; ++j) out[32*t+j] = lg[j] - lse;
}

extern "C" void kernel_launch(void* const* d_in, const int* in_sizes, int n_in,
                              void* d_out, int out_size, void* d_ws, size_t ws_size,
                              hipStream_t stream)
{
    const float* sent = (const float*)d_in[0];
    const float* wq   = (const float*)d_in[1];
    const float* Wf   = (const float*)d_in[2];  const float* bfv = (const float*)d_in[3];
    const float* Wi   = (const float*)d_in[4];  const float* bi  = (const float*)d_in[5];
    const float* Wu   = (const float*)d_in[6];  const float* bu  = (const float*)d_in[7];
    const float* Wo   = (const float*)d_in[8];  const float* bo  = (const float*)d_in[9];
    const float* thf  = (const float*)d_in[10]; const float* thi = (const float*)d_in[11];
    const float* thu  = (const float*)d_in[12]; const float* tho = (const float*)d_in[13];
    const float* Wt   = (const float*)d_in[14]; const float* bt  = (const float*)d_in[15];

    int S = in_sizes[0] / 8;                // 2048 (B = 1)
    if (S > MAXS) S = MAXS;
    float* outp = (float*)d_out;
    const int nseg = (S + SEG - 1) / SEG;   // 128 segments

    qcnn_kernel<<<(S + 3) / 4, 256, 0, stream>>>(sent, wq, Wf, bfv, Wi, bi,
                                                 Wu, bu, Wo, bo,
                                                 thf, thi, thu, tho, S);
    lstm_kernel<<<nseg, 64, 0, stream>>>(Wf, Wi, Wu, Wo, S);
    head_kernel<<<(S + 255) / 256, 256, 0, stream>>>(Wt, bt, outp, S);
}